// Round 1
// baseline (405.571 us; speedup 1.0000x reference)
//
#include <hip/hip_runtime.h>
#include <cfloat>

#define NB      20   // NUM_BINS
#define NBOUND  19   // NUM_BINS - 1
#define ED      768  // EMBED_DIM
#define ED4     192  // ED / 4
#define EPS     1e-8f

// One 64-lane wave handles one batch row:
//  - lanes 0..18 hold the 19 sorted boundaries for this row's code
//  - ballot+popcount = searchsorted(side='left')
//  - shfl broadcasts lo_b / hi_b; all lanes compute alpha uniformly
//  - each lane writes 3 float4 (192 float4 = 768 floats), stride-64 coalesced
__global__ __launch_bounds__(256) void sde_kernel(
    const float* __restrict__ values,
    const int*   __restrict__ code_ids,
    const float* __restrict__ boundaries,
    const float* __restrict__ embed_table,
    float*       __restrict__ out,
    int batch)
{
    const int wave = blockIdx.x * (blockDim.x >> 6) + (threadIdx.x >> 6);
    const int lane = threadIdx.x & 63;
    if (wave >= batch) return;
    const int b = wave;

    const float v = values[b];        // same addr across wave -> broadcast
    const int   c = code_ids[b];

    // lanes >= 19 hold +inf so they never count as "< v"
    float bnd = FLT_MAX;
    if (lane < NBOUND) bnd = boundaries[(size_t)c * NBOUND + lane];

    // searchsorted left: count of boundaries strictly less than v
    const unsigned long long lt = __ballot(bnd < v);
    const int idx = __popcll(lt);     // in [0, 19], uniform across wave

    // brows[clip(idx-1,0,18)] and brows[clip(idx,0,18)]
    int lo_i = idx - 1; lo_i = lo_i < 0 ? 0 : lo_i;          // <= 18 already
    int hi_i = idx > NBOUND - 1 ? NBOUND - 1 : idx;
    const float lo_b = __shfl(bnd, lo_i);
    const float hi_b = __shfl(bnd, hi_i);

    const bool interior = (idx > 0) && (idx < NB - 1);
    const float denom = hi_b - lo_b;
    const bool tiny = fabsf(denom) < EPS;

    float alpha = (v - lo_b) / (tiny ? 1.0f : denom);
    alpha = fminf(fmaxf(alpha, 0.0f), 1.0f);
    if (tiny)      alpha = 0.5f;
    if (!interior) alpha = 0.0f;

    const int lower = (idx == 0) ? 0 : ((idx >= NB - 1) ? NB - 1 : idx - 1);
    const int upper = interior ? idx : lower;

    const float4* __restrict__ tlo = (const float4*)(embed_table + (size_t)lower * ED);
    const float4* __restrict__ thi = (const float4*)(embed_table + (size_t)upper * ED);
    float4* __restrict__ orow = (float4*)(out + (size_t)b * ED);

    const float om = 1.0f - alpha;
    #pragma unroll
    for (int k = 0; k < 3; ++k) {
        const int s = lane + k * 64;
        const float4 e0 = tlo[s];
        const float4 e1 = thi[s];
        float4 r;
        r.x = om * e0.x + alpha * e1.x;
        r.y = om * e0.y + alpha * e1.y;
        r.z = om * e0.z + alpha * e1.z;
        r.w = om * e0.w + alpha * e1.w;
        orow[s] = r;
    }
}

extern "C" void kernel_launch(void* const* d_in, const int* in_sizes, int n_in,
                              void* d_out, int out_size, void* d_ws, size_t ws_size,
                              hipStream_t stream)
{
    const float* values     = (const float*)d_in[0];
    const int*   code_ids   = (const int*)  d_in[1];
    const float* boundaries = (const float*)d_in[2];
    const float* embed      = (const float*)d_in[3];
    float*       out        = (float*)d_out;

    const int batch = in_sizes[0];
    const int waves_per_block = 4;                 // 256 threads
    const int blocks = (batch + waves_per_block - 1) / waves_per_block;

    sde_kernel<<<blocks, 256, 0, stream>>>(values, code_ids, boundaries, embed, out, batch);
}